// Round 11
// baseline (355.638 us; speedup 1.0000x reference)
//
#include <hip/hip_runtime.h>

#define NN 2048
#define TT 64
#define FF 16
#define HH 64
#define LL 16
#define TOPKK 10
#define CAP 960

#define AS 72      // Asp row stride in shorts (144 B)
#define XAS 40     // xa row stride in shorts (80 B)
#define XPS 196    // xp row stride in floats

typedef __bf16 bf16x8 __attribute__((ext_vector_type(8)));
typedef float floatx4 __attribute__((ext_vector_type(4)));

union FragCast { uint4 u; bf16x8 b; unsigned short s[8]; };
union Pack4 { unsigned short s[4]; uint2 u; };

__device__ __forceinline__ unsigned short f2bf(float f) {
    unsigned u = __float_as_uint(f);
    return (unsigned short)((u + 0x7fff + ((u >> 16) & 1)) >> 16);
}
__device__ __forceinline__ float bf2f(unsigned short h) {
    return __uint_as_float(((unsigned)h) << 16);
}
__device__ __forceinline__ void split3(float v, unsigned short& a, unsigned short& b, unsigned short& c) {
    a = f2bf(v); float r = v - bf2f(a);
    b = f2bf(r); float r2 = r - bf2f(b);
    c = f2bf(r2);
}
__device__ __forceinline__ float fsigmoid(float x) {
    return __builtin_amdgcn_rcpf(1.f + __builtin_amdgcn_exp2f(-1.442695041f * x));
}
__device__ __forceinline__ float ftanh(float x) {
    return 1.f - 2.f * __builtin_amdgcn_rcpf(1.f + __builtin_amdgcn_exp2f(2.885390082f * x));
}
__device__ __forceinline__ void async_copy16(const void* g, void* l) {
    __builtin_amdgcn_global_load_lds(
        (const __attribute__((address_space(1))) unsigned int*)g,
        (__attribute__((address_space(3))) unsigned int*)l, 16, 0, 0);
}
#define MFMA16(A, B, C) __builtin_amdgcn_mfma_f32_16x16x32_bf16((A), (B), (C), 0, 0, 0)

// ---------------------------------------------------------------------------
// Kernel 1: MFMA GRU v5. 1024 blocks x 256 threads, 2 samples/block ->
// 4 blocks/CU (was 2). The GEMM->pointwise->GEMM chain is strictly serial
// within a block; doubling co-resident independent blocks halves exposed
// latency. M=16 tile half-duplicated: samples at D-rows {0,4}; rows {8,12}
// form an isolated self-feeding dup loop (bounded by sigmoid/tanh, gated off
// the global write) — costs MFMA FLOPs, buys TLP.
// ---------------------------------------------------------------------------
__global__ __launch_bounds__(256, 4) void gru_kernel(
    const float* __restrict__ x,      // (N,T,F)
    const float* __restrict__ W_ih,   // (192,16)
    const float* __restrict__ W_hh,   // (192,64)
    const float* __restrict__ b_ih,   // (192,)
    const float* __restrict__ b_hh,   // (192,)
    float* __restrict__ h_tail,       // (N,16,64)
    int* __restrict__ cnt)            // (2048,) zeroed here
{
    __shared__ __attribute__((aligned(16))) unsigned short Asp[2][3][16 * AS];
    __shared__ __attribute__((aligned(16))) unsigned short xa[3][16 * XAS];
    __shared__ __attribute__((aligned(16))) float xp[16 * XPS];
    __shared__ __attribute__((aligned(16))) float x_lds[2 * TT * FF];   // 8 KB

    const int t    = threadIdx.x;
    const int wv   = t >> 6;
    const int lane = t & 63;
    const int nh   = lane & 15;
    const int quad = lane >> 4;
    const int n0   = blockIdx.x * 2;

    if (t < 2) cnt[blockIdx.x * 2 + t] = 0;

    {
        const char* src = (const char*)(x + (size_t)n0 * TT * FF);
        char* dst = (char*)x_lds;
#pragma unroll
        for (int i = 0; i < 2; ++i)
            async_copy16(src + i * 4096 + t * 16, dst + i * 4096 + t * 16);
    }
    {
        unsigned* p = (unsigned*)&Asp[0][0][0];
        for (int i = t; i < 2 * 3 * 16 * AS / 2; i += 256) p[i] = 0;
        unsigned* q = (unsigned*)&xa[0][0];
        for (int i = t; i < 3 * 16 * XAS / 2; i += 256) q[i] = 0;
    }

    const int jb = wv * 16 + nh;
    const float brz = b_ih[jb] + b_hh[jb];
    const float bz  = b_ih[64 + jb] + b_hh[64 + jb];
    const float bxn = b_ih[128 + jb];
    const float bhn = b_hh[128 + jb];

    bf16x8 wf[3][2][3];
#pragma unroll
    for (int nt = 0; nt < 3; ++nt) {
        const int gr = (wv + 4 * nt) * 16 + nh;
#pragma unroll
        for (int kc = 0; kc < 2; ++kc) {
            const float* p = W_hh + gr * 64 + kc * 32 + quad * 8;
            FragCast f1, f2, f3;
#pragma unroll
            for (int i = 0; i < 8; ++i) split3(p[i], f1.s[i], f2.s[i], f3.s[i]);
            wf[nt][kc][0] = f1.b; wf[nt][kc][1] = f2.b; wf[nt][kc][2] = f3.b;
        }
    }
    bf16x8 wfi[3][3];
#pragma unroll
    for (int nt = 0; nt < 3; ++nt) {
        const int gr = (wv + 4 * nt) * 16 + nh;
        FragCast f1, f2, f3;
#pragma unroll
        for (int i = 0; i < 8; ++i) {
            const float v = (quad < 2) ? W_ih[gr * 16 + quad * 8 + i] : 0.f;
            split3(v, f1.s[i], f2.s[i], f3.s[i]);
        }
        wfi[nt][0] = f1.b; wfi[nt][1] = f2.b; wfi[nt][2] = f3.b;
    }

    __syncthreads();

    float hprev = 0.f;

    for (int chunk = 0; chunk < 16; ++chunk) {
        {
            const int row = t >> 4, f = t & 15;
            const int p = row & 3, sl = row >> 2;
            if (p < 2) {   // rows with p>=2 stay zero forever (dup slots)
                const float xv = x_lds[p * (TT * FF) + (chunk * 4 + sl) * FF + f];
                unsigned short a, b, c; split3(xv, a, b, c);
                xa[0][row * XAS + f] = a;
                xa[1][row * XAS + f] = b;
                xa[2][row * XAS + f] = c;
            }
        }
        __syncthreads();
        // xp = x_chunk @ W_ih^T, product-major A/B split (9+9 MFMAs)
        {
            floatx4 xA0 = {0,0,0,0}, xB0 = {0,0,0,0};
            floatx4 xA1 = {0,0,0,0}, xB1 = {0,0,0,0};
            floatx4 xA2 = {0,0,0,0}, xB2 = {0,0,0,0};
            const int aoff = nh * XAS + quad * 8;
            FragCast a1, a2, a3;
            a1.u = *(const uint4*)&xa[0][aoff];
            a2.u = *(const uint4*)&xa[1][aoff];
            a3.u = *(const uint4*)&xa[2][aoff];
            xA0 = MFMA16(a1.b, wfi[0][0], xA0); xA1 = MFMA16(a1.b, wfi[1][0], xA1); xA2 = MFMA16(a1.b, wfi[2][0], xA2);
            xB0 = MFMA16(a1.b, wfi[0][1], xB0); xB1 = MFMA16(a1.b, wfi[1][1], xB1); xB2 = MFMA16(a1.b, wfi[2][1], xB2);
            xB0 = MFMA16(a2.b, wfi[0][0], xB0); xB1 = MFMA16(a2.b, wfi[1][0], xB1); xB2 = MFMA16(a2.b, wfi[2][0], xB2);
            xA0 = MFMA16(a1.b, wfi[0][2], xA0); xA1 = MFMA16(a1.b, wfi[1][2], xA1); xA2 = MFMA16(a1.b, wfi[2][2], xA2);
            xA0 = MFMA16(a2.b, wfi[0][1], xA0); xA1 = MFMA16(a2.b, wfi[1][1], xA1); xA2 = MFMA16(a2.b, wfi[2][1], xA2);
            xB0 = MFMA16(a3.b, wfi[0][0], xB0); xB1 = MFMA16(a3.b, wfi[1][0], xB1); xB2 = MFMA16(a3.b, wfi[2][0], xB2);
#pragma unroll
            for (int r = 0; r < 4; ++r) {
                const int m = quad * 4 + r;
                xp[m * XPS + (wv + 0) * 16 + nh] = xA0[r] + xB0[r];
                xp[m * XPS + (wv + 4) * 16 + nh] = xA1[r] + xB1[r];
                xp[m * XPS + (wv + 8) * 16 + nh] = xA2[r] + xB2[r];
            }
        }
        __syncthreads();

#pragma unroll
        for (int si = 0; si < 4; ++si) {
            const int step = chunk * 4 + si;
            const int rb = step & 1, wb = rb ^ 1;
            floatx4 aA0 = {0,0,0,0}, aB0 = {0,0,0,0};
            floatx4 aA1 = {0,0,0,0}, aB1 = {0,0,0,0};
            floatx4 aA2 = {0,0,0,0}, aB2 = {0,0,0,0};
#pragma unroll
            for (int kc = 0; kc < 2; ++kc) {
                const int aoff = nh * AS + kc * 32 + quad * 8;
                FragCast a1, a2, a3;
                a1.u = *(const uint4*)&Asp[rb][0][aoff];
                a2.u = *(const uint4*)&Asp[rb][1][aoff];
                a3.u = *(const uint4*)&Asp[rb][2][aoff];
                aA0 = MFMA16(a1.b, wf[0][kc][0], aA0); aA1 = MFMA16(a1.b, wf[1][kc][0], aA1); aA2 = MFMA16(a1.b, wf[2][kc][0], aA2);
                aB0 = MFMA16(a1.b, wf[0][kc][1], aB0); aB1 = MFMA16(a1.b, wf[1][kc][1], aB1); aB2 = MFMA16(a1.b, wf[2][kc][1], aB2);
                aB0 = MFMA16(a2.b, wf[0][kc][0], aB0); aB1 = MFMA16(a2.b, wf[1][kc][0], aB1); aB2 = MFMA16(a2.b, wf[2][kc][0], aB2);
                aA0 = MFMA16(a1.b, wf[0][kc][2], aA0); aA1 = MFMA16(a1.b, wf[1][kc][2], aA1); aA2 = MFMA16(a1.b, wf[2][kc][2], aA2);
                aA0 = MFMA16(a2.b, wf[0][kc][1], aA0); aA1 = MFMA16(a2.b, wf[1][kc][1], aA1); aA2 = MFMA16(a2.b, wf[2][kc][1], aA2);
                aB0 = MFMA16(a3.b, wf[0][kc][0], aB0); aB1 = MFMA16(a3.b, wf[1][kc][0], aB1); aB2 = MFMA16(a3.b, wf[2][kc][0], aB2);
            }
            {
                const int xrow = si * 4 + quad;   // quads 2,3: xp rows are zero-x (dup loop)
                const float xr = xp[xrow * XPS + jb];
                const float xz = xp[xrow * XPS + 64 + jb];
                const float xn = xp[xrow * XPS + 128 + jb];
                const float rgt = fsigmoid((aA0[0] + aB0[0]) + xr + brz);
                const float zgt = fsigmoid((aA1[0] + aB1[0]) + xz + bz);
                const float ngt = ftanh((xn + bxn) + rgt * ((aA2[0] + aB2[0]) + bhn));
                const float h  = (1.f - zgt) * ngt + zgt * hprev;
                hprev = h;
                unsigned short la, lb2, lc; split3(h, la, lb2, lc);
                const int ho = (4 * quad) * AS + jb;
                Asp[wb][0][ho] = la;
                Asp[wb][1][ho] = lb2;
                Asp[wb][2][ho] = lc;
                if (quad < 2 && step >= TT - LL)
                    h_tail[((size_t)(n0 + quad) * LL + (step - (TT - LL))) * HH + jb] = h;
            }
            __syncthreads();
        }
    }
}

// ---------------------------------------------------------------------------
// Kernel 2: prep v5 (unchanged from R10).
// ---------------------------------------------------------------------------
__global__ __launch_bounds__(256, 2) void prep_kernel(
    const float* __restrict__ h_tail, // (32768,64)
    const float* __restrict__ Wk,     // (64,64)
    const float* __restrict__ Wq,     // (64,64)
    float* __restrict__ Kmat,         // (32768,64) fp32
    unsigned short* __restrict__ Kh,  // (32768,64) bf16
    float* __restrict__ Qf,           // (2048,64) fp32
    unsigned short* __restrict__ Qh)  // (2048,64) bf16
{
    __shared__ __attribute__((aligned(16))) float Wk_s[64 * 68];
    __shared__ __attribute__((aligned(16))) float Wq_s[64 * 69];
    __shared__ __attribute__((aligned(16))) float h_s[64 * 68];

    const int t = threadIdx.x;
    const size_t rbase = (size_t)blockIdx.x * 64;

#pragma unroll
    for (int k = 0; k < 4; ++k) {
        const int idx = t + k * 256;
        const int j = idx >> 4, ci = idx & 15;
        *(float4*)(h_s + j * 68 + ci * 4) = *(const float4*)(h_tail + (rbase + j) * 64 + ci * 4);
    }
    for (int c = t; c < 1024; c += 256) {
        const int j = c >> 4, ci = c & 15;
        *(float4*)(Wk_s + j * 68 + ((ci ^ (j >> 2)) << 2)) = *(const float4*)(Wk + c * 4);
    }
    for (int c = t; c < 4096; c += 256) {
        const int j = c >> 6, i = c & 63;
        Wq_s[j * 69 + i] = Wq[c];
    }
    __syncthreads();

    const int rg = t >> 4;
    const int cg = t & 15;
    float acc[4][4];
#pragma unroll
    for (int r = 0; r < 4; ++r)
#pragma unroll
        for (int c = 0; c < 4; ++c) acc[r][c] = 0.f;

#pragma unroll
    for (int ci = 0; ci < 16; ++ci) {
        float4 wv[4];
#pragma unroll
        for (int c = 0; c < 4; ++c) {
            const int j = cg * 4 + c;
            wv[c] = *(const float4*)(Wk_s + j * 68 + ((ci ^ cg) << 2));
        }
#pragma unroll
        for (int r = 0; r < 4; ++r) {
            const float4 hv = *(const float4*)(h_s + (rg * 4 + r) * 68 + ci * 4);
#pragma unroll
            for (int c = 0; c < 4; ++c)
                acc[r][c] += hv.x * wv[c].x + hv.y * wv[c].y
                           + hv.z * wv[c].z + hv.w * wv[c].w;
        }
    }
#pragma unroll
    for (int r = 0; r < 4; ++r) {
        const size_t row = rbase + rg * 4 + r;
        float4 o; o.x = acc[r][0]; o.y = acc[r][1]; o.z = acc[r][2]; o.w = acc[r][3];
        *(float4*)(Kmat + row * 64 + cg * 4) = o;
        Pack4 p;
#pragma unroll
        for (int c = 0; c < 4; ++c) p.s[c] = f2bf(acc[r][c]);
        *(uint2*)(Kh + row * 64 + cg * 4) = p.u;
    }

    {
        const int s = t >> 6, j = t & 63;
        const float* hr = h_s + (s * 16 + 15) * 68;
        float a0 = 0.f, a1 = 0.f;
#pragma unroll
        for (int i = 0; i < 64; i += 2) {
            a0 += hr[i] * Wq_s[j * 69 + i];
            a1 += hr[i + 1] * Wq_s[j * 69 + i + 1];
        }
        const float a = a0 + a1;
        const size_t qi = (size_t)(blockIdx.x * 4 + s) * 64 + j;
        Qf[qi] = a;
        Qh[qi] = f2bf(a);
    }
}

// ---------------------------------------------------------------------------
// Kernel 3: MFMA scores + threshold filter v2 (unchanged from R10).
// ---------------------------------------------------------------------------
__global__ __launch_bounds__(512, 4) void score_kernel(
    const unsigned short* __restrict__ Kh,  // (32768,64) bf16
    const unsigned short* __restrict__ Qh,  // (2048,64) bf16
    int* __restrict__ cnt,                  // (2048,)
    int* __restrict__ ids)                  // (2048, CAP)
{
    __shared__ float stat_s[8][4][16];
    __shared__ float stat_q[8][4][16];
    __shared__ float th_s[64];

    const int t    = threadIdx.x;
    const int wave = t >> 6;
    const int lane = t & 63;
    const int n    = lane & 15;
    const int quad = lane >> 4;

    const int qgroup = blockIdx.x >> 4;
    const int split  = blockIdx.x & 15;
    const int tile0  = split * 128 + wave * 16;

    FragCast bq[4][2];
#pragma unroll
    for (int qs = 0; qs < 4; ++qs) {
        const int qg = qgroup * 64 + qs * 16 + n;
        bq[qs][0].u = *(const uint4*)(Qh + (size_t)qg * 64 + quad * 8);
        bq[qs][1].u = *(const uint4*)(Qh + (size_t)qg * 64 + 32 + quad * 8);
    }

    float ssum[4] = {0.f,0.f,0.f,0.f}, ssq[4] = {0.f,0.f,0.f,0.f};
    for (int i = 0; i < 8; ++i) {
        const unsigned short* r = Kh + (size_t)((tile0 + i) * 16 + n) * 64;
        FragCast a0, a1;
        a0.u = *(const uint4*)(r + quad * 8);
        a1.u = *(const uint4*)(r + 32 + quad * 8);
#pragma unroll
        for (int qs = 0; qs < 4; ++qs) {
            floatx4 acc = {0.f, 0.f, 0.f, 0.f};
            acc = MFMA16(a0.b, bq[qs][0].b, acc);
            acc = MFMA16(a1.b, bq[qs][1].b, acc);
#pragma unroll
            for (int j = 0; j < 4; ++j) { ssum[qs] += acc[j]; ssq[qs] += acc[j] * acc[j]; }
        }
    }
#pragma unroll
    for (int qs = 0; qs < 4; ++qs) {
        ssum[qs] += __shfl_xor(ssum[qs], 16, 64); ssq[qs] += __shfl_xor(ssq[qs], 16, 64);
        ssum[qs] += __shfl_xor(ssum[qs], 32, 64); ssq[qs] += __shfl_xor(ssq[qs], 32, 64);
    }
    if (lane < 16) {
#pragma unroll
        for (int qs = 0; qs < 4; ++qs) { stat_s[wave][qs][n] = ssum[qs]; stat_q[wave][qs][n] = ssq[qs]; }
    }
    __syncthreads();
    if (t < 64) {
        const int qs = t >> 4, c = t & 15;
        float S = 0.f, S2 = 0.f;
#pragma unroll
        for (int w = 0; w < 8; ++w) { S += stat_s[w][qs][c]; S2 += stat_q[w][qs][c]; }
        const float inv = 1.f / 1024.f;
        const float mu = S * inv;
        float var = S2 * inv - mu * mu;
        var = var > 0.f ? var : 0.f;
        th_s[t] = mu + 2.6f * __fsqrt_rn(var);
    }
    __syncthreads();
    float th[4];
#pragma unroll
    for (int qs = 0; qs < 4; ++qs) th[qs] = th_s[qs * 16 + n];

    {
        FragCast a0, a1, na0, na1;
        const unsigned short* r0 = Kh + (size_t)(tile0 * 16 + n) * 64;
        a0.u = *(const uint4*)(r0 + quad * 8);
        a1.u = *(const uint4*)(r0 + 32 + quad * 8);
        for (int i = 0; i < 16; ++i) {
            if (i + 1 < 16) {
                const unsigned short* r = Kh + (size_t)((tile0 + i + 1) * 16 + n) * 64;
                na0.u = *(const uint4*)(r + quad * 8);
                na1.u = *(const uint4*)(r + 32 + quad * 8);
            }
            const int rowb = (tile0 + i) * 16 + quad * 4;
#pragma unroll
            for (int qs = 0; qs < 4; ++qs) {
                floatx4 acc = {0.f, 0.f, 0.f, 0.f};
                acc = MFMA16(a0.b, bq[qs][0].b, acc);
                acc = MFMA16(a1.b, bq[qs][1].b, acc);
                const int qg = qgroup * 64 + qs * 16 + n;
#pragma unroll
                for (int j = 0; j < 4; ++j) {
                    const float s = acc[j];
                    const int rowid = rowb + j;
                    if (s > th[qs] && (rowid >> 4) != qg) {
                        const int slot = atomicAdd(&cnt[qg], 1);
                        if (slot < CAP) ids[(size_t)qg * CAP + slot] = rowid;
                    }
                }
            }
            a0 = na0; a1 = na1;
        }
    }
}

// ---------------------------------------------------------------------------
// Kernel 4: final v3.1 (unchanged from R10).
// ---------------------------------------------------------------------------
__global__ __launch_bounds__(512) void final_kernel(
    const float* __restrict__ x,      // (N,T,F)
    const float* __restrict__ Qf,     // (2048,64)
    const float* __restrict__ Kmat,   // (32768,64)
    const int* __restrict__ cnt,
    const int* __restrict__ ids,
    const float* __restrict__ W1, const float* __restrict__ b1,
    const float* __restrict__ W2, const float* __restrict__ b2,
    float* __restrict__ out)          // (N,)
{
    const int t    = threadIdx.x;
    const int w    = t >> 6;
    const int lane = t & 63;
    const int grp  = lane >> 4;
    const int sl   = lane & 15;
    const int q    = blockIdx.x * 8 + w;

    const int mc0 = cnt[q];
    const int mc  = mc0 < CAP ? mc0 : CAP;
    const float4 qv = *(const float4*)(Qf + (size_t)q * 64 + sl * 4);
    const int* idq = ids + (size_t)q * CAP;

    float v[TOPKK]; int vid[TOPKK];
#pragma unroll
    for (int r = 0; r < TOPKK; ++r) { v[r] = -3e38f; vid[r] = -1; }
    float vmin = -3e38f; int imin = 0;

    for (int c = grp; c < mc; c += 4) {
        const int id = idq[c];
        const float4 kv = *(const float4*)(Kmat + (size_t)id * 64 + sl * 4);
        float p = qv.x * kv.x + qv.y * kv.y + qv.z * kv.z + qv.w * kv.w;
        p += __shfl_xor(p, 1, 64);
        p += __shfl_xor(p, 2, 64);
        p += __shfl_xor(p, 4, 64);
        p += __shfl_xor(p, 8, 64);
        if (sl == 0 && p > vmin) {
#pragma unroll
            for (int r = 0; r < TOPKK; ++r) if (r == imin) { v[r] = p; vid[r] = id; }
            vmin = v[0]; imin = 0;
#pragma unroll
            for (int r = 1; r < TOPKK; ++r) if (v[r] < vmin) { vmin = v[r]; imin = r; }
        }
    }

    float topv[TOPKK]; int topi[TOPKK];
    unsigned used = 0;
    for (int r = 0; r < TOPKK; ++r) {
        float bv = -3e38f; int bi = -1, bs = -1;
#pragma unroll
        for (int s = 0; s < TOPKK; ++s)
            if (!((used >> s) & 1) && v[s] > bv) { bv = v[s]; bi = vid[s]; bs = s; }
        const float mybv = bv; const int mybi = bi;
#pragma unroll
        for (int st = 16; st <= 32; st <<= 1) {
            const float ov = __shfl_xor(bv, st, 64);
            const int   oi = __shfl_xor(bi, st, 64);
            if (ov > bv || (ov == bv && oi > bi)) { bv = ov; bi = oi; }
        }
        topv[r] = bv; topi[r] = bi;
        if (bs >= 0 && mybv == bv && mybi == bi) used |= (1u << bs);
    }
#pragma unroll
    for (int r = 0; r < TOPKK; ++r) {
        topv[r] = __shfl(topv[r], 0, 64);
        topi[r] = __shfl(topi[r], 0, 64);
    }

    float mx = topv[0];
#pragma unroll
    for (int r = 1; r < TOPKK; ++r) mx = topv[r] > mx ? topv[r] : mx;
    float wgt[TOPKK]; float sw = 0.f;
#pragma unroll
    for (int r = 0; r < TOPKK; ++r) {
        wgt[r] = (topi[r] >= 0) ? __expf(topv[r] - mx) : 0.f;
        sw += wgt[r];
    }
    const float inv = 1.f / sw;

    float4 f0 = {0,0,0,0}, f1 = {0,0,0,0}, f2 = {0,0,0,0}, f3 = {0,0,0,0};
    if (lane < TOPKK && topi[lane] >= 0) {
        const int wi = topi[lane];
        const float* xr = x + ((size_t)(wi >> 4) * TT + 48 + (wi & 15)) * FF;
        const float s = wgt[lane] * inv;
        float4 a = *(const float4*)(xr);
        float4 b = *(const float4*)(xr + 4);
        float4 cc = *(const float4*)(xr + 8);
        float4 d = *(const float4*)(xr + 12);
        f0.x = s * a.x; f0.y = s * a.y; f0.z = s * a.z; f0.w = s * a.w;
        f1.x = s * b.x; f1.y = s * b.y; f1.z = s * b.z; f1.w = s * b.w;
        f2.x = s * cc.x; f2.y = s * cc.y; f2.z = s * cc.z; f2.w = s * cc.w;
        f3.x = s * d.x; f3.y = s * d.y; f3.z = s * d.z; f3.w = s * d.w;
    }
#pragma unroll
    for (int st = 1; st <= 8; st <<= 1) {
        f0.x += __shfl_xor(f0.x, st, 64); f0.y += __shfl_xor(f0.y, st, 64);
        f0.z += __shfl_xor(f0.z, st, 64); f0.w += __shfl_xor(f0.w, st, 64);
        f1.x += __shfl_xor(f1.x, st, 64); f1.y += __shfl_xor(f1.y, st, 64);
        f1.z += __shfl_xor(f1.z, st, 64); f1.w += __shfl_xor(f1.w, st, 64);
        f2.x += __shfl_xor(f2.x, st, 64); f2.y += __shfl_xor(f2.y, st, 64);
        f2.z += __shfl_xor(f2.z, st, 64); f2.w += __shfl_xor(f2.w, st, 64);
        f3.x += __shfl_xor(f3.x, st, 64); f3.y += __shfl_xor(f3.y, st, 64);
        f3.z += __shfl_xor(f3.z, st, 64); f3.w += __shfl_xor(f3.w, st, 64);
    }

    float o = 0.f;
    if (lane < 16) {
        const float* w1r = W1 + lane * 16;
        float hh = b1[lane]
            + f0.x * w1r[0]  + f0.y * w1r[1]  + f0.z * w1r[2]  + f0.w * w1r[3]
            + f1.x * w1r[4]  + f1.y * w1r[5]  + f1.z * w1r[6]  + f1.w * w1r[7]
            + f2.x * w1r[8]  + f2.y * w1r[9]  + f2.z * w1r[10] + f2.w * w1r[11]
            + f3.x * w1r[12] + f3.y * w1r[13] + f3.z * w1r[14] + f3.w * w1r[15];
        hh = hh > 0.f ? hh : 0.01f * hh;
        o = hh * W2[lane];
    }
#pragma unroll
    for (int st = 1; st <= 8; st <<= 1) o += __shfl_xor(o, st, 64);
    if (lane == 0) out[q] = o + b2[0];
}

// ---------------------------------------------------------------------------
extern "C" void kernel_launch(void* const* d_in, const int* in_sizes, int n_in,
                              void* d_out, int out_size, void* d_ws, size_t ws_size,
                              hipStream_t stream) {
    const float* x    = (const float*)d_in[0];
    const float* W_ih = (const float*)d_in[1];
    const float* W_hh = (const float*)d_in[2];
    const float* b_ih = (const float*)d_in[3];
    const float* b_hh = (const float*)d_in[4];
    const float* Wq   = (const float*)d_in[5];
    const float* Wk   = (const float*)d_in[6];
    const float* W1   = (const float*)d_in[7];
    const float* b1   = (const float*)d_in[8];
    const float* W2   = (const float*)d_in[9];
    const float* b2   = (const float*)d_in[10];
    float* outp = (float*)d_out;
    (void)ws_size; (void)n_in; (void)in_sizes; (void)out_size;

    float* h_tail        = (float*)d_ws;                                 // 8 MB
    int*   ids           = (int*)d_ws;                                   // overlay (after prep consumes h_tail)
    float* Kmat          = h_tail + (size_t)2048 * 1024;                 // 8 MB
    unsigned short* Kh   = (unsigned short*)(Kmat + (size_t)32768 * 64); // 4 MB
    float* Qf            = (float*)(Kh + (size_t)32768 * 64);            // 0.5 MB
    unsigned short* Qh   = (unsigned short*)(Qf + (size_t)2048 * 64);    // 0.25 MB
    int*   cnt           = (int*)(Qh + (size_t)2048 * 64);               // 8 KB

    gru_kernel<<<NN / 2, 256, 0, stream>>>(x, W_ih, W_hh, b_ih, b_hh, h_tail, cnt);
    prep_kernel<<<512, 256, 0, stream>>>(h_tail, Wk, Wq, Kmat, Kh, Qf, Qh);
    score_kernel<<<512, 512, 0, stream>>>(Kh, Qh, cnt, ids);
    final_kernel<<<NN / 8, 512, 0, stream>>>(x, Qf, Kmat, cnt, ids, W1, b1, W2, b2, outp);
}

// Round 12
// 255.177 us; speedup vs baseline: 1.3937x; 1.3937x over previous
//
#include <hip/hip_runtime.h>

#define NN 2048
#define TT 64
#define FF 16
#define HH 64
#define LL 16
#define TOPKK 10
#define CAP 960

#define AS 72      // Asp row stride in shorts (144 B)
#define XAS 40     // xa row stride in shorts (80 B)
#define XPS 196    // xp row stride in floats

typedef __bf16 bf16x8 __attribute__((ext_vector_type(8)));
typedef float floatx4 __attribute__((ext_vector_type(4)));

union FragCast { uint4 u; bf16x8 b; unsigned short s[8]; };
union Pack4 { unsigned short s[4]; uint2 u; };

__device__ __forceinline__ unsigned short f2bf(float f) {
    unsigned u = __float_as_uint(f);
    return (unsigned short)((u + 0x7fff + ((u >> 16) & 1)) >> 16);
}
__device__ __forceinline__ float bf2f(unsigned short h) {
    return __uint_as_float(((unsigned)h) << 16);
}
__device__ __forceinline__ void split3(float v, unsigned short& a, unsigned short& b, unsigned short& c) {
    a = f2bf(v); float r = v - bf2f(a);
    b = f2bf(r); float r2 = r - bf2f(b);
    c = f2bf(r2);
}
__device__ __forceinline__ float fsigmoid(float x) {
    return __builtin_amdgcn_rcpf(1.f + __builtin_amdgcn_exp2f(-1.442695041f * x));
}
__device__ __forceinline__ float ftanh(float x) {
    return 1.f - 2.f * __builtin_amdgcn_rcpf(1.f + __builtin_amdgcn_exp2f(2.885390082f * x));
}
__device__ __forceinline__ void async_copy16(const void* g, void* l) {
    __builtin_amdgcn_global_load_lds(
        (const __attribute__((address_space(1))) unsigned int*)g,
        (__attribute__((address_space(3))) unsigned int*)l, 16, 0, 0);
}
#define MFMA16(A, B, C) __builtin_amdgcn_mfma_f32_16x16x32_bf16((A), (B), (C), 0, 0, 0)

// ---------------------------------------------------------------------------
// Kernel 1: MFMA GRU v6 = R10's proven v4 (4 samples/block, 2 blocks/CU,
// launch_bounds(256,2) — R11 proved (256,4) spills the W registers) + FUSED
// K/Q projection epilogue (prep v5's exact math, h kept in LDS h_keep, no
// h_tail round-trip, prep dispatch eliminated). Single LDS arena: main-loop
// region (46.6 KB) is overlaid by Wk/Wq staging in the epilogue; h_keep
// (17 KB) persists. 62.5 KB total -> 2 blocks/CU.
// ---------------------------------------------------------------------------
__global__ __launch_bounds__(256, 2) void gru_kernel(
    const float* __restrict__ x,      // (N,T,F)
    const float* __restrict__ W_ih,   // (192,16)
    const float* __restrict__ W_hh,   // (192,64)
    const float* __restrict__ b_ih,   // (192,)
    const float* __restrict__ b_hh,   // (192,)
    const float* __restrict__ Wk,     // (64,64)
    const float* __restrict__ Wq,     // (64,64)
    float* __restrict__ Kmat,         // (32768,64) fp32
    unsigned short* __restrict__ Kh,  // (32768,64) bf16
    float* __restrict__ Qf,           // (2048,64) fp32
    unsigned short* __restrict__ Qh,  // (2048,64) bf16
    int* __restrict__ cnt)            // (2048,) zeroed here
{
    // arena layout (bytes):
    //   [0,13824)      Asp   [2][3][16*AS] shorts     (main loop)
    //   [13824,17664)  xa    [3][16*XAS] shorts       (main loop)
    //   [17664,30208)  xp    [16*XPS] floats          (main loop)
    //   [30208,46592)  x_lds [4*TT*FF] floats         (main loop)
    //   [46592,64000)  h_keep [64*68] floats          (persists into epilogue)
    // epilogue overlay on [0,46592): Wk_s [0,17408), Wq_s [17408,35072)
    __shared__ __attribute__((aligned(16))) char arena[64000];
    unsigned short* const Asp0 = (unsigned short*)arena;
    unsigned short* const xa0  = (unsigned short*)(arena + 13824);
    float* const xp            = (float*)(arena + 17664);
    float* const x_lds         = (float*)(arena + 30208);
    float* const h_keep        = (float*)(arena + 46592);
#define ASP(b, l, i) Asp0[((b) * 3 + (l)) * (16 * AS) + (i)]
#define XA(l, i)     xa0[(l) * (16 * XAS) + (i)]

    const int t    = threadIdx.x;
    const int wv   = t >> 6;
    const int lane = t & 63;
    const int nh   = lane & 15;
    const int quad = lane >> 4;
    const int n0   = blockIdx.x * 4;

    if (t < 4) cnt[blockIdx.x * 4 + t] = 0;

    {
        const char* src = (const char*)(x + (size_t)n0 * TT * FF);
        char* dst = (char*)x_lds;
#pragma unroll
        for (int i = 0; i < 4; ++i)
            async_copy16(src + i * 4096 + t * 16, dst + i * 4096 + t * 16);
    }
    {
        unsigned* p = (unsigned*)Asp0;
        for (int i = t; i < 3456; i += 256) p[i] = 0;   // 13824 B
        unsigned* q = (unsigned*)xa0;
        for (int i = t; i < 960; i += 256) q[i] = 0;    // 3840 B
    }

    const int jb = wv * 16 + nh;
    const float brz = b_ih[jb] + b_hh[jb];
    const float bz  = b_ih[64 + jb] + b_hh[64 + jb];
    const float bxn = b_ih[128 + jb];
    const float bhn = b_hh[128 + jb];

    bf16x8 wf[3][2][3];
#pragma unroll
    for (int nt = 0; nt < 3; ++nt) {
        const int gr = (wv + 4 * nt) * 16 + nh;
#pragma unroll
        for (int kc = 0; kc < 2; ++kc) {
            const float* p = W_hh + gr * 64 + kc * 32 + quad * 8;
            FragCast f1, f2, f3;
#pragma unroll
            for (int i = 0; i < 8; ++i) split3(p[i], f1.s[i], f2.s[i], f3.s[i]);
            wf[nt][kc][0] = f1.b; wf[nt][kc][1] = f2.b; wf[nt][kc][2] = f3.b;
        }
    }
    bf16x8 wfi[3][3];
#pragma unroll
    for (int nt = 0; nt < 3; ++nt) {
        const int gr = (wv + 4 * nt) * 16 + nh;
        FragCast f1, f2, f3;
#pragma unroll
        for (int i = 0; i < 8; ++i) {
            const float v = (quad < 2) ? W_ih[gr * 16 + quad * 8 + i] : 0.f;
            split3(v, f1.s[i], f2.s[i], f3.s[i]);
        }
        wfi[nt][0] = f1.b; wfi[nt][1] = f2.b; wfi[nt][2] = f3.b;
    }

    __syncthreads();

    float hprev = 0.f;

    for (int chunk = 0; chunk < 16; ++chunk) {
        {
            const int row = t >> 4, f = t & 15;
            const int p = row & 3, sl = row >> 2;
            const float xv = x_lds[p * (TT * FF) + (chunk * 4 + sl) * FF + f];
            unsigned short a, b, c; split3(xv, a, b, c);
            XA(0, row * XAS + f) = a;
            XA(1, row * XAS + f) = b;
            XA(2, row * XAS + f) = c;
        }
        __syncthreads();
        // xp = x_chunk @ W_ih^T, product-major A/B split
        {
            floatx4 xA0 = {0,0,0,0}, xB0 = {0,0,0,0};
            floatx4 xA1 = {0,0,0,0}, xB1 = {0,0,0,0};
            floatx4 xA2 = {0,0,0,0}, xB2 = {0,0,0,0};
            const int aoff = nh * XAS + quad * 8;
            FragCast a1, a2, a3;
            a1.u = *(const uint4*)&XA(0, aoff);
            a2.u = *(const uint4*)&XA(1, aoff);
            a3.u = *(const uint4*)&XA(2, aoff);
            xA0 = MFMA16(a1.b, wfi[0][0], xA0); xA1 = MFMA16(a1.b, wfi[1][0], xA1); xA2 = MFMA16(a1.b, wfi[2][0], xA2);
            xB0 = MFMA16(a1.b, wfi[0][1], xB0); xB1 = MFMA16(a1.b, wfi[1][1], xB1); xB2 = MFMA16(a1.b, wfi[2][1], xB2);
            xB0 = MFMA16(a2.b, wfi[0][0], xB0); xB1 = MFMA16(a2.b, wfi[1][0], xB1); xB2 = MFMA16(a2.b, wfi[2][0], xB2);
            xA0 = MFMA16(a1.b, wfi[0][2], xA0); xA1 = MFMA16(a1.b, wfi[1][2], xA1); xA2 = MFMA16(a1.b, wfi[2][2], xA2);
            xA0 = MFMA16(a2.b, wfi[0][1], xA0); xA1 = MFMA16(a2.b, wfi[1][1], xA1); xA2 = MFMA16(a2.b, wfi[2][1], xA2);
            xB0 = MFMA16(a3.b, wfi[0][0], xB0); xB1 = MFMA16(a3.b, wfi[1][0], xB1); xB2 = MFMA16(a3.b, wfi[2][0], xB2);
#pragma unroll
            for (int r = 0; r < 4; ++r) {
                const int m = quad * 4 + r;
                xp[m * XPS + (wv + 0) * 16 + nh] = xA0[r] + xB0[r];
                xp[m * XPS + (wv + 4) * 16 + nh] = xA1[r] + xB1[r];
                xp[m * XPS + (wv + 8) * 16 + nh] = xA2[r] + xB2[r];
            }
        }
        __syncthreads();

#pragma unroll
        for (int si = 0; si < 4; ++si) {
            const int step = chunk * 4 + si;
            const int rb = step & 1, wb = rb ^ 1;
            floatx4 aA0 = {0,0,0,0}, aB0 = {0,0,0,0};
            floatx4 aA1 = {0,0,0,0}, aB1 = {0,0,0,0};
            floatx4 aA2 = {0,0,0,0}, aB2 = {0,0,0,0};
#pragma unroll
            for (int kc = 0; kc < 2; ++kc) {
                const int aoff = nh * AS + kc * 32 + quad * 8;
                FragCast a1, a2, a3;
                a1.u = *(const uint4*)&ASP(rb, 0, aoff);
                a2.u = *(const uint4*)&ASP(rb, 1, aoff);
                a3.u = *(const uint4*)&ASP(rb, 2, aoff);
                aA0 = MFMA16(a1.b, wf[0][kc][0], aA0); aA1 = MFMA16(a1.b, wf[1][kc][0], aA1); aA2 = MFMA16(a1.b, wf[2][kc][0], aA2);
                aB0 = MFMA16(a1.b, wf[0][kc][1], aB0); aB1 = MFMA16(a1.b, wf[1][kc][1], aB1); aB2 = MFMA16(a1.b, wf[2][kc][1], aB2);
                aB0 = MFMA16(a2.b, wf[0][kc][0], aB0); aB1 = MFMA16(a2.b, wf[1][kc][0], aB1); aB2 = MFMA16(a2.b, wf[2][kc][0], aB2);
                aA0 = MFMA16(a1.b, wf[0][kc][2], aA0); aA1 = MFMA16(a1.b, wf[1][kc][2], aA1); aA2 = MFMA16(a1.b, wf[2][kc][2], aA2);
                aA0 = MFMA16(a2.b, wf[0][kc][1], aA0); aA1 = MFMA16(a2.b, wf[1][kc][1], aA1); aA2 = MFMA16(a2.b, wf[2][kc][1], aA2);
                aB0 = MFMA16(a3.b, wf[0][kc][0], aB0); aB1 = MFMA16(a3.b, wf[1][kc][0], aB1); aB2 = MFMA16(a3.b, wf[2][kc][0], aB2);
            }
            {
                const int xrow = si * 4 + quad;
                const float xr = xp[xrow * XPS + jb];
                const float xz = xp[xrow * XPS + 64 + jb];
                const float xn = xp[xrow * XPS + 128 + jb];
                const float rgt = fsigmoid((aA0[0] + aB0[0]) + xr + brz);
                const float zgt = fsigmoid((aA1[0] + aB1[0]) + xz + bz);
                const float ngt = ftanh((xn + bxn) + rgt * ((aA2[0] + aB2[0]) + bhn));
                const float h  = (1.f - zgt) * ngt + zgt * hprev;
                hprev = h;
                unsigned short la, lb2, lc; split3(h, la, lb2, lc);
                const int ho = (4 * quad) * AS + jb;
                ASP(wb, 0, ho) = la;
                ASP(wb, 1, ho) = lb2;
                ASP(wb, 2, ho) = lc;
                if (step >= TT - LL)
                    h_keep[(quad * 16 + (step - (TT - LL))) * 68 + jb] = h;   // LDS, not global
            }
            __syncthreads();
        }
    }

    // ===== fused prep epilogue (prep v5 math, h from h_keep) =====
    float* const Wk_s = (float*)arena;            // overlay: main-loop region is dead
    float* const Wq_s = (float*)(arena + 17408);
    for (int c = t; c < 1024; c += 256) {
        const int j = c >> 4, ci = c & 15;
        *(float4*)(Wk_s + j * 68 + ((ci ^ (j >> 2)) << 2)) = *(const float4*)(Wk + c * 4);
    }
    for (int c = t; c < 4096; c += 256) {
        const int j = c >> 6, i = c & 63;
        Wq_s[j * 69 + i] = Wq[c];
    }
    __syncthreads();

    {
        const int rg = t >> 4, cg = t & 15;
        const size_t rbase = (size_t)blockIdx.x * 64;
        float acc[4][4];
#pragma unroll
        for (int r = 0; r < 4; ++r)
#pragma unroll
            for (int c = 0; c < 4; ++c) acc[r][c] = 0.f;

#pragma unroll
        for (int ci = 0; ci < 16; ++ci) {
            float4 wvv[4];
#pragma unroll
            for (int c = 0; c < 4; ++c) {
                const int j = cg * 4 + c;     // j>>2 == cg
                wvv[c] = *(const float4*)(Wk_s + j * 68 + ((ci ^ cg) << 2));
            }
#pragma unroll
            for (int r = 0; r < 4; ++r) {
                const float4 hv = *(const float4*)(h_keep + (rg * 4 + r) * 68 + ci * 4);
#pragma unroll
                for (int c = 0; c < 4; ++c)
                    acc[r][c] += hv.x * wvv[c].x + hv.y * wvv[c].y
                               + hv.z * wvv[c].z + hv.w * wvv[c].w;
            }
        }
#pragma unroll
        for (int r = 0; r < 4; ++r) {
            const size_t row = rbase + rg * 4 + r;
            float4 o; o.x = acc[r][0]; o.y = acc[r][1]; o.z = acc[r][2]; o.w = acc[r][3];
            *(float4*)(Kmat + row * 64 + cg * 4) = o;
            Pack4 p;
#pragma unroll
            for (int c = 0; c < 4; ++c) p.s[c] = f2bf(acc[r][c]);
            *(uint2*)(Kh + row * 64 + cg * 4) = p.u;
        }

        // Q: 4 samples x 64 cols, one per thread (h row wave-uniform broadcast)
        const int s = t >> 6, j = t & 63;
        const float* hr = h_keep + (s * 16 + 15) * 68;
        float a0 = 0.f, a1 = 0.f;
#pragma unroll
        for (int i = 0; i < 64; i += 2) {
            a0 += hr[i] * Wq_s[j * 69 + i];
            a1 += hr[i + 1] * Wq_s[j * 69 + i + 1];
        }
        const float a = a0 + a1;
        const size_t qi = (size_t)(blockIdx.x * 4 + s) * 64 + j;
        Qf[qi] = a;
        Qh[qi] = f2bf(a);
    }
#undef ASP
#undef XA
}

// ---------------------------------------------------------------------------
// Kernel 2: MFMA scores + threshold filter v2 (unchanged from R10 — control).
// ---------------------------------------------------------------------------
__global__ __launch_bounds__(512, 4) void score_kernel(
    const unsigned short* __restrict__ Kh,  // (32768,64) bf16
    const unsigned short* __restrict__ Qh,  // (2048,64) bf16
    int* __restrict__ cnt,                  // (2048,)
    int* __restrict__ ids)                  // (2048, CAP)
{
    __shared__ float stat_s[8][4][16];
    __shared__ float stat_q[8][4][16];
    __shared__ float th_s[64];

    const int t    = threadIdx.x;
    const int wave = t >> 6;
    const int lane = t & 63;
    const int n    = lane & 15;
    const int quad = lane >> 4;

    const int qgroup = blockIdx.x >> 4;
    const int split  = blockIdx.x & 15;
    const int tile0  = split * 128 + wave * 16;

    FragCast bq[4][2];
#pragma unroll
    for (int qs = 0; qs < 4; ++qs) {
        const int qg = qgroup * 64 + qs * 16 + n;
        bq[qs][0].u = *(const uint4*)(Qh + (size_t)qg * 64 + quad * 8);
        bq[qs][1].u = *(const uint4*)(Qh + (size_t)qg * 64 + 32 + quad * 8);
    }

    float ssum[4] = {0.f,0.f,0.f,0.f}, ssq[4] = {0.f,0.f,0.f,0.f};
    for (int i = 0; i < 8; ++i) {
        const unsigned short* r = Kh + (size_t)((tile0 + i) * 16 + n) * 64;
        FragCast a0, a1;
        a0.u = *(const uint4*)(r + quad * 8);
        a1.u = *(const uint4*)(r + 32 + quad * 8);
#pragma unroll
        for (int qs = 0; qs < 4; ++qs) {
            floatx4 acc = {0.f, 0.f, 0.f, 0.f};
            acc = MFMA16(a0.b, bq[qs][0].b, acc);
            acc = MFMA16(a1.b, bq[qs][1].b, acc);
#pragma unroll
            for (int j = 0; j < 4; ++j) { ssum[qs] += acc[j]; ssq[qs] += acc[j] * acc[j]; }
        }
    }
#pragma unroll
    for (int qs = 0; qs < 4; ++qs) {
        ssum[qs] += __shfl_xor(ssum[qs], 16, 64); ssq[qs] += __shfl_xor(ssq[qs], 16, 64);
        ssum[qs] += __shfl_xor(ssum[qs], 32, 64); ssq[qs] += __shfl_xor(ssq[qs], 32, 64);
    }
    if (lane < 16) {
#pragma unroll
        for (int qs = 0; qs < 4; ++qs) { stat_s[wave][qs][n] = ssum[qs]; stat_q[wave][qs][n] = ssq[qs]; }
    }
    __syncthreads();
    if (t < 64) {
        const int qs = t >> 4, c = t & 15;
        float S = 0.f, S2 = 0.f;
#pragma unroll
        for (int w = 0; w < 8; ++w) { S += stat_s[w][qs][c]; S2 += stat_q[w][qs][c]; }
        const float inv = 1.f / 1024.f;
        const float mu = S * inv;
        float var = S2 * inv - mu * mu;
        var = var > 0.f ? var : 0.f;
        th_s[t] = mu + 2.6f * __fsqrt_rn(var);
    }
    __syncthreads();
    float th[4];
#pragma unroll
    for (int qs = 0; qs < 4; ++qs) th[qs] = th_s[qs * 16 + n];

    {
        FragCast a0, a1, na0, na1;
        const unsigned short* r0 = Kh + (size_t)(tile0 * 16 + n) * 64;
        a0.u = *(const uint4*)(r0 + quad * 8);
        a1.u = *(const uint4*)(r0 + 32 + quad * 8);
        for (int i = 0; i < 16; ++i) {
            if (i + 1 < 16) {
                const unsigned short* r = Kh + (size_t)((tile0 + i + 1) * 16 + n) * 64;
                na0.u = *(const uint4*)(r + quad * 8);
                na1.u = *(const uint4*)(r + 32 + quad * 8);
            }
            const int rowb = (tile0 + i) * 16 + quad * 4;
#pragma unroll
            for (int qs = 0; qs < 4; ++qs) {
                floatx4 acc = {0.f, 0.f, 0.f, 0.f};
                acc = MFMA16(a0.b, bq[qs][0].b, acc);
                acc = MFMA16(a1.b, bq[qs][1].b, acc);
                const int qg = qgroup * 64 + qs * 16 + n;
#pragma unroll
                for (int j = 0; j < 4; ++j) {
                    const float s = acc[j];
                    const int rowid = rowb + j;
                    if (s > th[qs] && (rowid >> 4) != qg) {
                        const int slot = atomicAdd(&cnt[qg], 1);
                        if (slot < CAP) ids[(size_t)qg * CAP + slot] = rowid;
                    }
                }
            }
            a0 = na0; a1 = na1;
        }
    }
}

// ---------------------------------------------------------------------------
// Kernel 3: final v4 — wave-per-query, 512 blocks x 256 threads (4 q/block),
// software-pipelined candidate loop (prefetch next id + K row during the
// current shfl-reduce) to break the serial id->row->reduce latency chain.
// ---------------------------------------------------------------------------
__global__ __launch_bounds__(256) void final_kernel(
    const float* __restrict__ x,      // (N,T,F)
    const float* __restrict__ Qf,     // (2048,64)
    const float* __restrict__ Kmat,   // (32768,64)
    const int* __restrict__ cnt,
    const int* __restrict__ ids,
    const float* __restrict__ W1, const float* __restrict__ b1,
    const float* __restrict__ W2, const float* __restrict__ b2,
    float* __restrict__ out)          // (N,)
{
    const int t    = threadIdx.x;
    const int w    = t >> 6;
    const int lane = t & 63;
    const int grp  = lane >> 4;
    const int sl   = lane & 15;
    const int q    = blockIdx.x * 4 + w;

    const int mc0 = cnt[q];
    const int mc  = mc0 < CAP ? mc0 : CAP;
    const float4 qv = *(const float4*)(Qf + (size_t)q * 64 + sl * 4);
    const int* idq = ids + (size_t)q * CAP;

    float v[TOPKK]; int vid[TOPKK];
#pragma unroll
    for (int r = 0; r < TOPKK; ++r) { v[r] = -3e38f; vid[r] = -1; }
    float vmin = -3e38f; int imin = 0;

    int idc = -1; float4 kvc = {0, 0, 0, 0};
    if (grp < mc) {
        idc = idq[grp];
        kvc = *(const float4*)(Kmat + (size_t)idc * 64 + sl * 4);
    }
    for (int c = grp; c < mc; c += 4) {
        // prefetch next candidate while reducing the current one
        int idn = -1; float4 kvn = {0, 0, 0, 0};
        if (c + 4 < mc) {
            idn = idq[c + 4];
            kvn = *(const float4*)(Kmat + (size_t)idn * 64 + sl * 4);
        }
        float p = qv.x * kvc.x + qv.y * kvc.y + qv.z * kvc.z + qv.w * kvc.w;
        p += __shfl_xor(p, 1, 64);
        p += __shfl_xor(p, 2, 64);
        p += __shfl_xor(p, 4, 64);
        p += __shfl_xor(p, 8, 64);
        if (sl == 0 && p > vmin) {
#pragma unroll
            for (int r = 0; r < TOPKK; ++r) if (r == imin) { v[r] = p; vid[r] = idc; }
            vmin = v[0]; imin = 0;
#pragma unroll
            for (int r = 1; r < TOPKK; ++r) if (v[r] < vmin) { vmin = v[r]; imin = r; }
        }
        idc = idn; kvc = kvn;
    }

    // 10-round merge across holder lanes (0,16,32,48)
    float topv[TOPKK]; int topi[TOPKK];
    unsigned used = 0;
    for (int r = 0; r < TOPKK; ++r) {
        float bv = -3e38f; int bi = -1, bs = -1;
#pragma unroll
        for (int s = 0; s < TOPKK; ++s)
            if (!((used >> s) & 1) && v[s] > bv) { bv = v[s]; bi = vid[s]; bs = s; }
        const float mybv = bv; const int mybi = bi;
#pragma unroll
        for (int st = 16; st <= 32; st <<= 1) {
            const float ov = __shfl_xor(bv, st, 64);
            const int   oi = __shfl_xor(bi, st, 64);
            if (ov > bv || (ov == bv && oi > bi)) { bv = ov; bi = oi; }
        }
        topv[r] = bv; topi[r] = bi;
        if (bs >= 0 && mybv == bv && mybi == bi) used |= (1u << bs);
    }
    // broadcast merged list from lane 0 (R9 fix)
#pragma unroll
    for (int r = 0; r < TOPKK; ++r) {
        topv[r] = __shfl(topv[r], 0, 64);
        topi[r] = __shfl(topi[r], 0, 64);
    }

    float mx = topv[0];
#pragma unroll
    for (int r = 1; r < TOPKK; ++r) mx = topv[r] > mx ? topv[r] : mx;
    float wgt[TOPKK]; float sw = 0.f;
#pragma unroll
    for (int r = 0; r < TOPKK; ++r) {
        wgt[r] = (topi[r] >= 0) ? __expf(topv[r] - mx) : 0.f;
        sw += wgt[r];
    }
    const float inv = 1.f / sw;

    float4 f0 = {0,0,0,0}, f1 = {0,0,0,0}, f2 = {0,0,0,0}, f3 = {0,0,0,0};
    if (lane < TOPKK && topi[lane] >= 0) {
        const int wi = topi[lane];
        const float* xr = x + ((size_t)(wi >> 4) * TT + 48 + (wi & 15)) * FF;
        const float s = wgt[lane] * inv;
        float4 a = *(const float4*)(xr);
        float4 b = *(const float4*)(xr + 4);
        float4 cc = *(const float4*)(xr + 8);
        float4 d = *(const float4*)(xr + 12);
        f0.x = s * a.x; f0.y = s * a.y; f0.z = s * a.z; f0.w = s * a.w;
        f1.x = s * b.x; f1.y = s * b.y; f1.z = s * b.z; f1.w = s * b.w;
        f2.x = s * cc.x; f2.y = s * cc.y; f2.z = s * cc.z; f2.w = s * cc.w;
        f3.x = s * d.x; f3.y = s * d.y; f3.z = s * d.z; f3.w = s * d.w;
    }
#pragma unroll
    for (int st = 1; st <= 8; st <<= 1) {
        f0.x += __shfl_xor(f0.x, st, 64); f0.y += __shfl_xor(f0.y, st, 64);
        f0.z += __shfl_xor(f0.z, st, 64); f0.w += __shfl_xor(f0.w, st, 64);
        f1.x += __shfl_xor(f1.x, st, 64); f1.y += __shfl_xor(f1.y, st, 64);
        f1.z += __shfl_xor(f1.z, st, 64); f1.w += __shfl_xor(f1.w, st, 64);
        f2.x += __shfl_xor(f2.x, st, 64); f2.y += __shfl_xor(f2.y, st, 64);
        f2.z += __shfl_xor(f2.z, st, 64); f2.w += __shfl_xor(f2.w, st, 64);
        f3.x += __shfl_xor(f3.x, st, 64); f3.y += __shfl_xor(f3.y, st, 64);
        f3.z += __shfl_xor(f3.z, st, 64); f3.w += __shfl_xor(f3.w, st, 64);
    }

    float o = 0.f;
    if (lane < 16) {
        const float* w1r = W1 + lane * 16;
        float hh = b1[lane]
            + f0.x * w1r[0]  + f0.y * w1r[1]  + f0.z * w1r[2]  + f0.w * w1r[3]
            + f1.x * w1r[4]  + f1.y * w1r[5]  + f1.z * w1r[6]  + f1.w * w1r[7]
            + f2.x * w1r[8]  + f2.y * w1r[9]  + f2.z * w1r[10] + f2.w * w1r[11]
            + f3.x * w1r[12] + f3.y * w1r[13] + f3.z * w1r[14] + f3.w * w1r[15];
        hh = hh > 0.f ? hh : 0.01f * hh;
        o = hh * W2[lane];
    }
#pragma unroll
    for (int st = 1; st <= 8; st <<= 1) o += __shfl_xor(o, st, 64);
    if (lane == 0) out[q] = o + b2[0];
}

// ---------------------------------------------------------------------------
extern "C" void kernel_launch(void* const* d_in, const int* in_sizes, int n_in,
                              void* d_out, int out_size, void* d_ws, size_t ws_size,
                              hipStream_t stream) {
    const float* x    = (const float*)d_in[0];
    const float* W_ih = (const float*)d_in[1];
    const float* W_hh = (const float*)d_in[2];
    const float* b_ih = (const float*)d_in[3];
    const float* b_hh = (const float*)d_in[4];
    const float* Wq   = (const float*)d_in[5];
    const float* Wk   = (const float*)d_in[6];
    const float* W1   = (const float*)d_in[7];
    const float* b1   = (const float*)d_in[8];
    const float* W2   = (const float*)d_in[9];
    const float* b2   = (const float*)d_in[10];
    float* outp = (float*)d_out;
    (void)ws_size; (void)n_in; (void)in_sizes; (void)out_size;

    int*   ids           = (int*)d_ws;                                   // 7.86 MB
    float* Kmat          = (float*)d_ws + (size_t)2048 * 1024;           // at 8 MB offset
    unsigned short* Kh   = (unsigned short*)(Kmat + (size_t)32768 * 64); // 4 MB
    float* Qf            = (float*)(Kh + (size_t)32768 * 64);            // 0.5 MB
    unsigned short* Qh   = (unsigned short*)(Qf + (size_t)2048 * 64);    // 0.25 MB
    int*   cnt           = (int*)(Qh + (size_t)2048 * 64);               // 8 KB

    gru_kernel<<<NN / 4, 256, 0, stream>>>(x, W_ih, W_hh, b_ih, b_hh, Wk, Wq,
                                           Kmat, Kh, Qf, Qh, cnt);
    score_kernel<<<512, 512, 0, stream>>>(Kh, Qh, cnt, ids);
    final_kernel<<<NN / 4, 256, 0, stream>>>(x, Qf, Kmat, cnt, ids, W1, b1, W2, b2, outp);
}

// Round 13
// 221.528 us; speedup vs baseline: 1.6054x; 1.1519x over previous
//
#include <hip/hip_runtime.h>

#define NN 2048
#define TT 64
#define FF 16
#define HH 64
#define LL 16
#define TOPKK 10
#define CAP 960
#define LCAP 48   // per-block per-query LDS candidate cap (Poisson mean 9.6)

#define AS 72      // Asp row stride in shorts (144 B)
#define XAS 40     // xa row stride in shorts (80 B)
#define XPS 196    // xp row stride in floats

typedef __bf16 bf16x8 __attribute__((ext_vector_type(8)));
typedef float floatx4 __attribute__((ext_vector_type(4)));

union FragCast { uint4 u; bf16x8 b; unsigned short s[8]; };
union Pack4 { unsigned short s[4]; uint2 u; };

__device__ __forceinline__ unsigned short f2bf(float f) {
    unsigned u = __float_as_uint(f);
    return (unsigned short)((u + 0x7fff + ((u >> 16) & 1)) >> 16);
}
__device__ __forceinline__ float bf2f(unsigned short h) {
    return __uint_as_float(((unsigned)h) << 16);
}
__device__ __forceinline__ void split3(float v, unsigned short& a, unsigned short& b, unsigned short& c) {
    a = f2bf(v); float r = v - bf2f(a);
    b = f2bf(r); float r2 = r - bf2f(b);
    c = f2bf(r2);
}
__device__ __forceinline__ float fsigmoid(float x) {
    return __builtin_amdgcn_rcpf(1.f + __builtin_amdgcn_exp2f(-1.442695041f * x));
}
__device__ __forceinline__ float ftanh(float x) {
    return 1.f - 2.f * __builtin_amdgcn_rcpf(1.f + __builtin_amdgcn_exp2f(2.885390082f * x));
}
__device__ __forceinline__ void async_copy16(const void* g, void* l) {
    __builtin_amdgcn_global_load_lds(
        (const __attribute__((address_space(1))) unsigned int*)g,
        (__attribute__((address_space(3))) unsigned int*)l, 16, 0, 0);
}
#define MFMA16(A, B, C) __builtin_amdgcn_mfma_f32_16x16x32_bf16((A), (B), (C), 0, 0, 0)

// ---------------------------------------------------------------------------
// Kernel 1: MFMA GRU v6 + fused K/Q projection epilogue (unchanged from R12).
// ---------------------------------------------------------------------------
__global__ __launch_bounds__(256, 2) void gru_kernel(
    const float* __restrict__ x,      // (N,T,F)
    const float* __restrict__ W_ih,   // (192,16)
    const float* __restrict__ W_hh,   // (192,64)
    const float* __restrict__ b_ih,   // (192,)
    const float* __restrict__ b_hh,   // (192,)
    const float* __restrict__ Wk,     // (64,64)
    const float* __restrict__ Wq,     // (64,64)
    float* __restrict__ Kmat,         // (32768,64) fp32
    unsigned short* __restrict__ Kh,  // (32768,64) bf16
    float* __restrict__ Qf,           // (2048,64) fp32
    unsigned short* __restrict__ Qh,  // (2048,64) bf16
    int* __restrict__ cnt)            // (2048,) zeroed here
{
    __shared__ __attribute__((aligned(16))) char arena[64000];
    unsigned short* const Asp0 = (unsigned short*)arena;
    unsigned short* const xa0  = (unsigned short*)(arena + 13824);
    float* const xp            = (float*)(arena + 17664);
    float* const x_lds         = (float*)(arena + 30208);
    float* const h_keep        = (float*)(arena + 46592);
#define ASP(b, l, i) Asp0[((b) * 3 + (l)) * (16 * AS) + (i)]
#define XA(l, i)     xa0[(l) * (16 * XAS) + (i)]

    const int t    = threadIdx.x;
    const int wv   = t >> 6;
    const int lane = t & 63;
    const int nh   = lane & 15;
    const int quad = lane >> 4;
    const int n0   = blockIdx.x * 4;

    if (t < 4) cnt[blockIdx.x * 4 + t] = 0;

    {
        const char* src = (const char*)(x + (size_t)n0 * TT * FF);
        char* dst = (char*)x_lds;
#pragma unroll
        for (int i = 0; i < 4; ++i)
            async_copy16(src + i * 4096 + t * 16, dst + i * 4096 + t * 16);
    }
    {
        unsigned* p = (unsigned*)Asp0;
        for (int i = t; i < 3456; i += 256) p[i] = 0;
        unsigned* q = (unsigned*)xa0;
        for (int i = t; i < 960; i += 256) q[i] = 0;
    }

    const int jb = wv * 16 + nh;
    const float brz = b_ih[jb] + b_hh[jb];
    const float bz  = b_ih[64 + jb] + b_hh[64 + jb];
    const float bxn = b_ih[128 + jb];
    const float bhn = b_hh[128 + jb];

    bf16x8 wf[3][2][3];
#pragma unroll
    for (int nt = 0; nt < 3; ++nt) {
        const int gr = (wv + 4 * nt) * 16 + nh;
#pragma unroll
        for (int kc = 0; kc < 2; ++kc) {
            const float* p = W_hh + gr * 64 + kc * 32 + quad * 8;
            FragCast f1, f2, f3;
#pragma unroll
            for (int i = 0; i < 8; ++i) split3(p[i], f1.s[i], f2.s[i], f3.s[i]);
            wf[nt][kc][0] = f1.b; wf[nt][kc][1] = f2.b; wf[nt][kc][2] = f3.b;
        }
    }
    bf16x8 wfi[3][3];
#pragma unroll
    for (int nt = 0; nt < 3; ++nt) {
        const int gr = (wv + 4 * nt) * 16 + nh;
        FragCast f1, f2, f3;
#pragma unroll
        for (int i = 0; i < 8; ++i) {
            const float v = (quad < 2) ? W_ih[gr * 16 + quad * 8 + i] : 0.f;
            split3(v, f1.s[i], f2.s[i], f3.s[i]);
        }
        wfi[nt][0] = f1.b; wfi[nt][1] = f2.b; wfi[nt][2] = f3.b;
    }

    __syncthreads();

    float hprev = 0.f;

    for (int chunk = 0; chunk < 16; ++chunk) {
        {
            const int row = t >> 4, f = t & 15;
            const int p = row & 3, sl = row >> 2;
            const float xv = x_lds[p * (TT * FF) + (chunk * 4 + sl) * FF + f];
            unsigned short a, b, c; split3(xv, a, b, c);
            XA(0, row * XAS + f) = a;
            XA(1, row * XAS + f) = b;
            XA(2, row * XAS + f) = c;
        }
        __syncthreads();
        {
            floatx4 xA0 = {0,0,0,0}, xB0 = {0,0,0,0};
            floatx4 xA1 = {0,0,0,0}, xB1 = {0,0,0,0};
            floatx4 xA2 = {0,0,0,0}, xB2 = {0,0,0,0};
            const int aoff = nh * XAS + quad * 8;
            FragCast a1, a2, a3;
            a1.u = *(const uint4*)&XA(0, aoff);
            a2.u = *(const uint4*)&XA(1, aoff);
            a3.u = *(const uint4*)&XA(2, aoff);
            xA0 = MFMA16(a1.b, wfi[0][0], xA0); xA1 = MFMA16(a1.b, wfi[1][0], xA1); xA2 = MFMA16(a1.b, wfi[2][0], xA2);
            xB0 = MFMA16(a1.b, wfi[0][1], xB0); xB1 = MFMA16(a1.b, wfi[1][1], xB1); xB2 = MFMA16(a1.b, wfi[2][1], xB2);
            xB0 = MFMA16(a2.b, wfi[0][0], xB0); xB1 = MFMA16(a2.b, wfi[1][0], xB1); xB2 = MFMA16(a2.b, wfi[2][0], xB2);
            xA0 = MFMA16(a1.b, wfi[0][2], xA0); xA1 = MFMA16(a1.b, wfi[1][2], xA1); xA2 = MFMA16(a1.b, wfi[2][2], xA2);
            xA0 = MFMA16(a2.b, wfi[0][1], xA0); xA1 = MFMA16(a2.b, wfi[1][1], xA1); xA2 = MFMA16(a2.b, wfi[2][1], xA2);
            xB0 = MFMA16(a3.b, wfi[0][0], xB0); xB1 = MFMA16(a3.b, wfi[1][0], xB1); xB2 = MFMA16(a3.b, wfi[2][0], xB2);
#pragma unroll
            for (int r = 0; r < 4; ++r) {
                const int m = quad * 4 + r;
                xp[m * XPS + (wv + 0) * 16 + nh] = xA0[r] + xB0[r];
                xp[m * XPS + (wv + 4) * 16 + nh] = xA1[r] + xB1[r];
                xp[m * XPS + (wv + 8) * 16 + nh] = xA2[r] + xB2[r];
            }
        }
        __syncthreads();

#pragma unroll
        for (int si = 0; si < 4; ++si) {
            const int step = chunk * 4 + si;
            const int rb = step & 1, wb = rb ^ 1;
            floatx4 aA0 = {0,0,0,0}, aB0 = {0,0,0,0};
            floatx4 aA1 = {0,0,0,0}, aB1 = {0,0,0,0};
            floatx4 aA2 = {0,0,0,0}, aB2 = {0,0,0,0};
#pragma unroll
            for (int kc = 0; kc < 2; ++kc) {
                const int aoff = nh * AS + kc * 32 + quad * 8;
                FragCast a1, a2, a3;
                a1.u = *(const uint4*)&ASP(rb, 0, aoff);
                a2.u = *(const uint4*)&ASP(rb, 1, aoff);
                a3.u = *(const uint4*)&ASP(rb, 2, aoff);
                aA0 = MFMA16(a1.b, wf[0][kc][0], aA0); aA1 = MFMA16(a1.b, wf[1][kc][0], aA1); aA2 = MFMA16(a1.b, wf[2][kc][0], aA2);
                aB0 = MFMA16(a1.b, wf[0][kc][1], aB0); aB1 = MFMA16(a1.b, wf[1][kc][1], aB1); aB2 = MFMA16(a1.b, wf[2][kc][1], aB2);
                aB0 = MFMA16(a2.b, wf[0][kc][0], aB0); aB1 = MFMA16(a2.b, wf[1][kc][0], aB1); aB2 = MFMA16(a2.b, wf[2][kc][0], aB2);
                aA0 = MFMA16(a1.b, wf[0][kc][2], aA0); aA1 = MFMA16(a1.b, wf[1][kc][2], aA1); aA2 = MFMA16(a1.b, wf[2][kc][2], aA2);
                aA0 = MFMA16(a2.b, wf[0][kc][1], aA0); aA1 = MFMA16(a2.b, wf[1][kc][1], aA1); aA2 = MFMA16(a2.b, wf[2][kc][1], aA2);
                aB0 = MFMA16(a3.b, wf[0][kc][0], aB0); aB1 = MFMA16(a3.b, wf[1][kc][0], aB1); aB2 = MFMA16(a3.b, wf[2][kc][0], aB2);
            }
            {
                const int xrow = si * 4 + quad;
                const float xr = xp[xrow * XPS + jb];
                const float xz = xp[xrow * XPS + 64 + jb];
                const float xn = xp[xrow * XPS + 128 + jb];
                const float rgt = fsigmoid((aA0[0] + aB0[0]) + xr + brz);
                const float zgt = fsigmoid((aA1[0] + aB1[0]) + xz + bz);
                const float ngt = ftanh((xn + bxn) + rgt * ((aA2[0] + aB2[0]) + bhn));
                const float h  = (1.f - zgt) * ngt + zgt * hprev;
                hprev = h;
                unsigned short la, lb2, lc; split3(h, la, lb2, lc);
                const int ho = (4 * quad) * AS + jb;
                ASP(wb, 0, ho) = la;
                ASP(wb, 1, ho) = lb2;
                ASP(wb, 2, ho) = lc;
                if (step >= TT - LL)
                    h_keep[(quad * 16 + (step - (TT - LL))) * 68 + jb] = h;
            }
            __syncthreads();
        }
    }

    // ===== fused prep epilogue =====
    float* const Wk_s = (float*)arena;
    float* const Wq_s = (float*)(arena + 17408);
    for (int c = t; c < 1024; c += 256) {
        const int j = c >> 4, ci = c & 15;
        *(float4*)(Wk_s + j * 68 + ((ci ^ (j >> 2)) << 2)) = *(const float4*)(Wk + c * 4);
    }
    for (int c = t; c < 4096; c += 256) {
        const int j = c >> 6, i = c & 63;
        Wq_s[j * 69 + i] = Wq[c];
    }
    __syncthreads();

    {
        const int rg = t >> 4, cg = t & 15;
        const size_t rbase = (size_t)blockIdx.x * 64;
        float acc[4][4];
#pragma unroll
        for (int r = 0; r < 4; ++r)
#pragma unroll
            for (int c = 0; c < 4; ++c) acc[r][c] = 0.f;

#pragma unroll
        for (int ci = 0; ci < 16; ++ci) {
            float4 wvv[4];
#pragma unroll
            for (int c = 0; c < 4; ++c) {
                const int j = cg * 4 + c;
                wvv[c] = *(const float4*)(Wk_s + j * 68 + ((ci ^ cg) << 2));
            }
#pragma unroll
            for (int r = 0; r < 4; ++r) {
                const float4 hv = *(const float4*)(h_keep + (rg * 4 + r) * 68 + ci * 4);
#pragma unroll
                for (int c = 0; c < 4; ++c)
                    acc[r][c] += hv.x * wvv[c].x + hv.y * wvv[c].y
                               + hv.z * wvv[c].z + hv.w * wvv[c].w;
            }
        }
#pragma unroll
        for (int r = 0; r < 4; ++r) {
            const size_t row = rbase + rg * 4 + r;
            float4 o; o.x = acc[r][0]; o.y = acc[r][1]; o.z = acc[r][2]; o.w = acc[r][3];
            *(float4*)(Kmat + row * 64 + cg * 4) = o;
            Pack4 p;
#pragma unroll
            for (int c = 0; c < 4; ++c) p.s[c] = f2bf(acc[r][c]);
            *(uint2*)(Kh + row * 64 + cg * 4) = p.u;
        }

        const int s = t >> 6, j = t & 63;
        const float* hr = h_keep + (s * 16 + 15) * 68;
        float a0 = 0.f, a1 = 0.f;
#pragma unroll
        for (int i = 0; i < 64; i += 2) {
            a0 += hr[i] * Wq_s[j * 69 + i];
            a1 += hr[i + 1] * Wq_s[j * 69 + i + 1];
        }
        const float a = a0 + a1;
        const size_t qi = (size_t)(blockIdx.x * 4 + s) * 64 + j;
        Qf[qi] = a;
        Qh[qi] = f2bf(a);
    }
#undef ASP
#undef XA
}

// ---------------------------------------------------------------------------
// Kernel 2: score v3 — LDS-buffered candidate emission. The R10-R12 version
// did one device-scope atomicAdd-with-return (~900 cyc) per emit inside the
// hot loop (315k total on 64 cache lines). Now: LDS atomics (~30 cyc) into
// per-block buffers, one global atomic per (block,query) at flush (32k),
// exact-overflow fallback to the old path (P(overflow) ~ 1e-9).
// ---------------------------------------------------------------------------
__global__ __launch_bounds__(512, 4) void score_kernel(
    const unsigned short* __restrict__ Kh,  // (32768,64) bf16
    const unsigned short* __restrict__ Qh,  // (2048,64) bf16
    int* __restrict__ cnt,                  // (2048,)
    int* __restrict__ ids)                  // (2048, CAP)
{
    __shared__ float stat_s[8][4][16];
    __shared__ float stat_q[8][4][16];
    __shared__ float th_s[64];
    __shared__ int   lcnt[64];
    __shared__ int   lids[64][LCAP];

    const int t    = threadIdx.x;
    const int wave = t >> 6;
    const int lane = t & 63;
    const int n    = lane & 15;
    const int quad = lane >> 4;

    const int qgroup = blockIdx.x >> 4;
    const int split  = blockIdx.x & 15;
    const int tile0  = split * 128 + wave * 16;

    FragCast bq[4][2];
#pragma unroll
    for (int qs = 0; qs < 4; ++qs) {
        const int qg = qgroup * 64 + qs * 16 + n;
        bq[qs][0].u = *(const uint4*)(Qh + (size_t)qg * 64 + quad * 8);
        bq[qs][1].u = *(const uint4*)(Qh + (size_t)qg * 64 + 32 + quad * 8);
    }
    if (t < 64) lcnt[t] = 0;

    float ssum[4] = {0.f,0.f,0.f,0.f}, ssq[4] = {0.f,0.f,0.f,0.f};
    for (int i = 0; i < 8; ++i) {
        const unsigned short* r = Kh + (size_t)((tile0 + i) * 16 + n) * 64;
        FragCast a0, a1;
        a0.u = *(const uint4*)(r + quad * 8);
        a1.u = *(const uint4*)(r + 32 + quad * 8);
#pragma unroll
        for (int qs = 0; qs < 4; ++qs) {
            floatx4 acc = {0.f, 0.f, 0.f, 0.f};
            acc = MFMA16(a0.b, bq[qs][0].b, acc);
            acc = MFMA16(a1.b, bq[qs][1].b, acc);
#pragma unroll
            for (int j = 0; j < 4; ++j) { ssum[qs] += acc[j]; ssq[qs] += acc[j] * acc[j]; }
        }
    }
#pragma unroll
    for (int qs = 0; qs < 4; ++qs) {
        ssum[qs] += __shfl_xor(ssum[qs], 16, 64); ssq[qs] += __shfl_xor(ssq[qs], 16, 64);
        ssum[qs] += __shfl_xor(ssum[qs], 32, 64); ssq[qs] += __shfl_xor(ssq[qs], 32, 64);
    }
    if (lane < 16) {
#pragma unroll
        for (int qs = 0; qs < 4; ++qs) { stat_s[wave][qs][n] = ssum[qs]; stat_q[wave][qs][n] = ssq[qs]; }
    }
    __syncthreads();
    if (t < 64) {
        const int qs = t >> 4, c = t & 15;
        float S = 0.f, S2 = 0.f;
#pragma unroll
        for (int w = 0; w < 8; ++w) { S += stat_s[w][qs][c]; S2 += stat_q[w][qs][c]; }
        const float inv = 1.f / 1024.f;
        const float mu = S * inv;
        float var = S2 * inv - mu * mu;
        var = var > 0.f ? var : 0.f;
        th_s[t] = mu + 2.6f * __fsqrt_rn(var);
    }
    __syncthreads();
    float th[4];
#pragma unroll
    for (int qs = 0; qs < 4; ++qs) th[qs] = th_s[qs * 16 + n];

    // Pass B: 16 tiles, LDS-buffered emit
    {
        FragCast a0, a1, na0, na1;
        const unsigned short* r0 = Kh + (size_t)(tile0 * 16 + n) * 64;
        a0.u = *(const uint4*)(r0 + quad * 8);
        a1.u = *(const uint4*)(r0 + 32 + quad * 8);
        for (int i = 0; i < 16; ++i) {
            if (i + 1 < 16) {
                const unsigned short* r = Kh + (size_t)((tile0 + i + 1) * 16 + n) * 64;
                na0.u = *(const uint4*)(r + quad * 8);
                na1.u = *(const uint4*)(r + 32 + quad * 8);
            }
            const int rowb = (tile0 + i) * 16 + quad * 4;
#pragma unroll
            for (int qs = 0; qs < 4; ++qs) {
                floatx4 acc = {0.f, 0.f, 0.f, 0.f};
                acc = MFMA16(a0.b, bq[qs][0].b, acc);
                acc = MFMA16(a1.b, bq[qs][1].b, acc);
                const int ql = qs * 16 + n;
                const int qg = qgroup * 64 + ql;
#pragma unroll
                for (int j = 0; j < 4; ++j) {
                    const float s = acc[j];
                    const int rowid = rowb + j;
                    if (s > th[qs] && (rowid >> 4) != qg) {
                        const int sl2 = atomicAdd(&lcnt[ql], 1);
                        if (sl2 < LCAP) {
                            lids[ql][sl2] = rowid;
                        } else {   // exact-overflow fallback (astronomically rare)
                            const int gs = atomicAdd(&cnt[qg], 1);
                            if (gs < CAP) ids[(size_t)qg * CAP + gs] = rowid;
                        }
                    }
                }
            }
            a0 = na0; a1 = na1;
        }
    }
    __syncthreads();
    // flush: one global atomic per (block, query), coalesced-ish id copy
    if (t < 64) {
        int lc = lcnt[t];
        lc = lc < LCAP ? lc : LCAP;
        if (lc > 0) {
            const int qg = qgroup * 64 + t;
            const int base = atomicAdd(&cnt[qg], lc);
            for (int k = 0; k < lc; ++k) {
                const int slot = base + k;
                if (slot < CAP) ids[(size_t)qg * CAP + slot] = lids[t][k];
            }
        }
    }
}

// ---------------------------------------------------------------------------
// Kernel 3: final v4 (unchanged from R12 — control variable).
// ---------------------------------------------------------------------------
__global__ __launch_bounds__(256) void final_kernel(
    const float* __restrict__ x,      // (N,T,F)
    const float* __restrict__ Qf,     // (2048,64)
    const float* __restrict__ Kmat,   // (32768,64)
    const int* __restrict__ cnt,
    const int* __restrict__ ids,
    const float* __restrict__ W1, const float* __restrict__ b1,
    const float* __restrict__ W2, const float* __restrict__ b2,
    float* __restrict__ out)          // (N,)
{
    const int t    = threadIdx.x;
    const int w    = t >> 6;
    const int lane = t & 63;
    const int grp  = lane >> 4;
    const int sl   = lane & 15;
    const int q    = blockIdx.x * 4 + w;

    const int mc0 = cnt[q];
    const int mc  = mc0 < CAP ? mc0 : CAP;
    const float4 qv = *(const float4*)(Qf + (size_t)q * 64 + sl * 4);
    const int* idq = ids + (size_t)q * CAP;

    float v[TOPKK]; int vid[TOPKK];
#pragma unroll
    for (int r = 0; r < TOPKK; ++r) { v[r] = -3e38f; vid[r] = -1; }
    float vmin = -3e38f; int imin = 0;

    int idc = -1; float4 kvc = {0, 0, 0, 0};
    if (grp < mc) {
        idc = idq[grp];
        kvc = *(const float4*)(Kmat + (size_t)idc * 64 + sl * 4);
    }
    for (int c = grp; c < mc; c += 4) {
        int idn = -1; float4 kvn = {0, 0, 0, 0};
        if (c + 4 < mc) {
            idn = idq[c + 4];
            kvn = *(const float4*)(Kmat + (size_t)idn * 64 + sl * 4);
        }
        float p = qv.x * kvc.x + qv.y * kvc.y + qv.z * kvc.z + qv.w * kvc.w;
        p += __shfl_xor(p, 1, 64);
        p += __shfl_xor(p, 2, 64);
        p += __shfl_xor(p, 4, 64);
        p += __shfl_xor(p, 8, 64);
        if (sl == 0 && p > vmin) {
#pragma unroll
            for (int r = 0; r < TOPKK; ++r) if (r == imin) { v[r] = p; vid[r] = idc; }
            vmin = v[0]; imin = 0;
#pragma unroll
            for (int r = 1; r < TOPKK; ++r) if (v[r] < vmin) { vmin = v[r]; imin = r; }
        }
        idc = idn; kvc = kvn;
    }

    float topv[TOPKK]; int topi[TOPKK];
    unsigned used = 0;
    for (int r = 0; r < TOPKK; ++r) {
        float bv = -3e38f; int bi = -1, bs = -1;
#pragma unroll
        for (int s = 0; s < TOPKK; ++s)
            if (!((used >> s) & 1) && v[s] > bv) { bv = v[s]; bi = vid[s]; bs = s; }
        const float mybv = bv; const int mybi = bi;
#pragma unroll
        for (int st = 16; st <= 32; st <<= 1) {
            const float ov = __shfl_xor(bv, st, 64);
            const int   oi = __shfl_xor(bi, st, 64);
            if (ov > bv || (ov == bv && oi > bi)) { bv = ov; bi = oi; }
        }
        topv[r] = bv; topi[r] = bi;
        if (bs >= 0 && mybv == bv && mybi == bi) used |= (1u << bs);
    }
#pragma unroll
    for (int r = 0; r < TOPKK; ++r) {
        topv[r] = __shfl(topv[r], 0, 64);
        topi[r] = __shfl(topi[r], 0, 64);
    }

    float mx = topv[0];
#pragma unroll
    for (int r = 1; r < TOPKK; ++r) mx = topv[r] > mx ? topv[r] : mx;
    float wgt[TOPKK]; float sw = 0.f;
#pragma unroll
    for (int r = 0; r < TOPKK; ++r) {
        wgt[r] = (topi[r] >= 0) ? __expf(topv[r] - mx) : 0.f;
        sw += wgt[r];
    }
    const float inv = 1.f / sw;

    float4 f0 = {0,0,0,0}, f1 = {0,0,0,0}, f2 = {0,0,0,0}, f3 = {0,0,0,0};
    if (lane < TOPKK && topi[lane] >= 0) {
        const int wi = topi[lane];
        const float* xr = x + ((size_t)(wi >> 4) * TT + 48 + (wi & 15)) * FF;
        const float s = wgt[lane] * inv;
        float4 a = *(const float4*)(xr);
        float4 b = *(const float4*)(xr + 4);
        float4 cc = *(const float4*)(xr + 8);
        float4 d = *(const float4*)(xr + 12);
        f0.x = s * a.x; f0.y = s * a.y; f0.z = s * a.z; f0.w = s * a.w;
        f1.x = s * b.x; f1.y = s * b.y; f1.z = s * b.z; f1.w = s * b.w;
        f2.x = s * cc.x; f2.y = s * cc.y; f2.z = s * cc.z; f2.w = s * cc.w;
        f3.x = s * d.x; f3.y = s * d.y; f3.z = s * d.z; f3.w = s * d.w;
    }
#pragma unroll
    for (int st = 1; st <= 8; st <<= 1) {
        f0.x += __shfl_xor(f0.x, st, 64); f0.y += __shfl_xor(f0.y, st, 64);
        f0.z += __shfl_xor(f0.z, st, 64); f0.w += __shfl_xor(f0.w, st, 64);
        f1.x += __shfl_xor(f1.x, st, 64); f1.y += __shfl_xor(f1.y, st, 64);
        f1.z += __shfl_xor(f1.z, st, 64); f1.w += __shfl_xor(f1.w, st, 64);
        f2.x += __shfl_xor(f2.x, st, 64); f2.y += __shfl_xor(f2.y, st, 64);
        f2.z += __shfl_xor(f2.z, st, 64); f2.w += __shfl_xor(f2.w, st, 64);
        f3.x += __shfl_xor(f3.x, st, 64); f3.y += __shfl_xor(f3.y, st, 64);
        f3.z += __shfl_xor(f3.z, st, 64); f3.w += __shfl_xor(f3.w, st, 64);
    }

    float o = 0.f;
    if (lane < 16) {
        const float* w1r = W1 + lane * 16;
        float hh = b1[lane]
            + f0.x * w1r[0]  + f0.y * w1r[1]  + f0.z * w1r[2]  + f0.w * w1r[3]
            + f1.x * w1r[4]  + f1.y * w1r[5]  + f1.z * w1r[6]  + f1.w * w1r[7]
            + f2.x * w1r[8]  + f2.y * w1r[9]  + f2.z * w1r[10] + f2.w * w1r[11]
            + f3.x * w1r[12] + f3.y * w1r[13] + f3.z * w1r[14] + f3.w * w1r[15];
        hh = hh > 0.f ? hh : 0.01f * hh;
        o = hh * W2[lane];
    }
#pragma unroll
    for (int st = 1; st <= 8; st <<= 1) o += __shfl_xor(o, st, 64);
    if (lane == 0) out[q] = o + b2[0];
}

// ---------------------------------------------------------------------------
extern "C" void kernel_launch(void* const* d_in, const int* in_sizes, int n_in,
                              void* d_out, int out_size, void* d_ws, size_t ws_size,
                              hipStream_t stream) {
    const float* x    = (const float*)d_in[0];
    const float* W_ih = (const float*)d_in[1];
    const float* W_hh = (const float*)d_in[2];
    const float* b_ih = (const float*)d_in[3];
    const float* b_hh = (const float*)d_in[4];
    const float* Wq   = (const float*)d_in[5];
    const float* Wk   = (const float*)d_in[6];
    const float* W1   = (const float*)d_in[7];
    const float* b1   = (const float*)d_in[8];
    const float* W2   = (const float*)d_in[9];
    const float* b2   = (const float*)d_in[10];
    float* outp = (float*)d_out;
    (void)ws_size; (void)n_in; (void)in_sizes; (void)out_size;

    int*   ids           = (int*)d_ws;                                   // 7.86 MB
    float* Kmat          = (float*)d_ws + (size_t)2048 * 1024;           // at 8 MB offset
    unsigned short* Kh   = (unsigned short*)(Kmat + (size_t)32768 * 64); // 4 MB
    float* Qf            = (float*)(Kh + (size_t)32768 * 64);            // 0.5 MB
    unsigned short* Qh   = (unsigned short*)(Qf + (size_t)2048 * 64);    // 0.25 MB
    int*   cnt           = (int*)(Qh + (size_t)2048 * 64);               // 8 KB

    gru_kernel<<<NN / 4, 256, 0, stream>>>(x, W_ih, W_hh, b_ih, b_hh, Wk, Wq,
                                           Kmat, Kh, Qf, Qh, cnt);
    score_kernel<<<512, 512, 0, stream>>>(Kh, Qh, cnt, ids);
    final_kernel<<<NN / 4, 256, 0, stream>>>(x, Qf, Kmat, cnt, ids, W1, b1, W2, b2, outp);
}